// Round 3
// baseline (305.386 us; speedup 1.0000x reference)
//
#include <hip/hip_runtime.h>
#include <hip/hip_bf16.h>
#include <stdint.h>

typedef __attribute__((ext_vector_type(8))) __bf16 bf16x8;
typedef __attribute__((ext_vector_type(4))) float f32x4_t;
typedef __attribute__((ext_vector_type(2))) unsigned int u32x2;
typedef __attribute__((ext_vector_type(4))) unsigned int u32x4;
typedef unsigned int uint32;

#define EPSC 1e-6f

__device__ __forceinline__ unsigned short f2bf(float x){
  return __builtin_bit_cast(unsigned short, (__bf16)x);
}
__device__ __forceinline__ uint32 pk2(float a, float b){
  return (uint32)f2bf(a) | ((uint32)f2bf(b) << 16);
}

// ---------------- zero_de: de[0..4095] = 0 ----------------
__global__ void zero_de(float* __restrict__ de){
  de[blockIdx.x*256 + threadIdx.x] = 0.f;
}

// ---------------- prep: WT[f][c] = bf16(W[c][f]) ----------------
__global__ void prep_wt(const float* __restrict__ W, unsigned short* __restrict__ WT){
  int c = blockIdx.x;   // 0..255
  int f = threadIdx.x;  // 0..255
  WT[(size_t)f*256 + c] = f2bf(W[(size_t)c*256 + f]);
}

// ---------------- deg: dv row sums -> rsqrt; de col sums (atomics); Hb = bf16(H) ----------------
// grid 512, block 256; each block: 32 rows of H
__global__ void deg_kernel(const float* __restrict__ H, float* __restrict__ dvs, float* __restrict__ de,
                           unsigned short* __restrict__ Hb){
  __shared__ float sm[32*256];
  const int t = threadIdx.x;
  const int n0 = blockIdx.x * 32;
  const int r = t >> 3, q = t & 7;
  float rp = 0.f;
  for (int ch = 0; ch < 16; ++ch){
    const float* base = H + (size_t)(n0 + r)*4096 + ch*256;
    unsigned short* hb = Hb + (size_t)(n0 + r)*4096 + ch*256;
    #pragma unroll
    for (int i = 0; i < 8; ++i){
      f32x4_t v = *(const f32x4_t*)(base + q*4 + 32*i);
      rp += v[0]+v[1]+v[2]+v[3];
      *(f32x4_t*)(sm + r*256 + q*4 + 32*i) = v;
      *(u32x2*)(hb + q*4 + 32*i) = u32x2{pk2(v[0], v[1]), pk2(v[2], v[3])};
    }
    __syncthreads();
    float cs = 0.f;
    #pragma unroll 8
    for (int rr = 0; rr < 32; ++rr) cs += sm[rr*256 + t];
    atomicAdd(de + ch*256 + t, cs);
    __syncthreads();
  }
  sm[t] = rp;
  __syncthreads();
  if (t < 32){
    float s = 0.f;
    #pragma unroll
    for (int j = 0; j < 8; ++j) s += sm[t*8 + j];
    dvs[n0 + t] = rsqrtf(s + EPSC);
  }
}

// ---------------- unified MFMA GEMM ----------------
// C[M,256] = A[M,K] @ BT[256,K]^T. BT bf16 (global_load_lds, XOR-swizzled source).
// Block 256 thr = 4 waves; tile BM=64 x BN=256, BK=32, double-buffered.
// TRANS=0,ABF16=0: A f32 row-major, reg-staged with f32->bf16 convert.
// TRANS=0,ABF16=1: A bf16 row-major, staged via global_load_lds (pre-swizzled source).
// TRANS=1,ABF16=1: A-logical = Asrc^T (Asrc bf16 [k][m]), shuffle-transpose staging.
// EPI=0: store f32 partial to Cpart + s*(NMT*64)*256 (split-K, no atomics).
// EPI=1: scale rows by dvs, store bf16 transposed to XsT[f][n] (stride 16384).
template<int TRANS, int ABF16, int EPI, int LDA, int KB, int NMT, int CHUNK>
__global__ __launch_bounds__(256, 2)
void gemm_k(const void* __restrict__ Asrc, const unsigned short* __restrict__ BT,
            float* __restrict__ Cpart, const float* __restrict__ dvs, unsigned short* __restrict__ XsT)
{
  constexpr bool GLA = (TRANS == 0 && ABF16 == 1);
  constexpr int NIT = CHUNK / 32;
  constexpr int ASZ = 64*32*2;     // 4096 B per A buffer
  constexpr int BSZ = 256*32*2;    // 16384 B per B buffer
  __shared__ __align__(16) char lds[2*ASZ + 2*BSZ];

  const float* Af = (const float*)Asrc;
  const unsigned short* Ah = (const unsigned short*)Asrc;

  const int t = threadIdx.x;
  const int lane = t & 63;
  const int w = t >> 6;            // 0..3 (wave = one 64-col slice of F)
  const int mt = blockIdx.x % NMT;
  const int s  = blockIdx.x / NMT;
  const int k0 = s * CHUNK;

  // staging coords
  const int st_r  = t >> 2, st_cq = t & 3;     // f32 straight: row 0..63, col-quarter
  const int tr_nl = t >> 3, tr_q  = t & 7;     // bf16 trans: n 0..31, e-octet 0..7

  f32x4_t acc[4][4] = {};
  f32x4_t pa[2];    // f32 straight staging regs
  u32x4  paw;       // bf16 trans staging regs (8 halves)

  auto loadA = [&](int it){
    if (TRANS == 0 && !ABF16){
      const float* p = Af + (size_t)(mt*64 + st_r)*LDA + k0 + it*32 + st_cq*4;
      pa[0] = *(const f32x4_t*)(p);
      pa[1] = *(const f32x4_t*)(p + 16);
    } else if (TRANS == 1){
      paw = *(const u32x4*)(Ah + (size_t)(k0 + it*32 + tr_nl)*LDA + mt*64 + tr_q*8);
    }
  };

  auto gllA = [&](int it, int buf){   // TRANS=0, bf16 A via global_load_lds
    char* ab = lds + buf*ASZ;
    const int kcur = k0 + it*32;
    const int arow = lane >> 2;                      // 0..15 within wave's 16-row slab
    const int kqs  = (lane & 3) ^ ((lane >> 2) & 3); // pre-swizzled source quarter
    const unsigned short* src = Ah + (size_t)(mt*64 + w*16 + arow)*LDA + kcur + kqs*8;
    __builtin_amdgcn_global_load_lds((const __attribute__((address_space(1))) void*)src,
                                     (__attribute__((address_space(3))) void*)(ab + w*1024),
                                     16, 0, 0);
  };

  auto gllB = [&](int it, int buf){
    char* bb = lds + 2*ASZ + buf*BSZ;
    const int kcur = k0 + it*32;
    const int swzh = ((lane & 3) ^ ((lane >> 2) & 3)) << 3;  // halfword offset => 16B XOR swizzle
    #pragma unroll
    for (int j = 0; j < 4; ++j){
      int chunk = w*4 + j;                       // 0..15, each = 16 rows (1KB)
      int frow = chunk*16 + (lane >> 2);
      const unsigned short* src = BT + (size_t)frow*KB + kcur + swzh;
      __builtin_amdgcn_global_load_lds((const __attribute__((address_space(1))) void*)src,
                                       (__attribute__((address_space(3))) void*)(bb + chunk*1024),
                                       16, 0, 0);
    }
  };

  auto stageA = [&](int buf){
    char* ab = lds + buf*ASZ;
    if (TRANS == 0 && !ABF16){
      #pragma unroll
      for (int i = 0; i < 2; ++i){
        int f4 = st_cq + 4*i;
        uint32 lo = pk2(pa[i][0], pa[i][1]);
        uint32 hi = pk2(pa[i][2], pa[i][3]);
        *(u32x2*)(ab + st_r*64 + ((f4*8) ^ ((st_r & 3) << 4))) = u32x2{lo, hi};
      }
    } else if (TRANS == 1){
      const bool odd = tr_nl & 1;
      const int np = t >> 4;                     // n-pair index 0..15
      uint32 pw[4];
      #pragma unroll
      for (int j = 0; j < 4; ++j) pw[j] = (uint32)__shfl_xor((int)paw[j], 8);
      #pragma unroll
      for (int j = 0; j < 4; ++j){
        int e = tr_q*8 + 2*j + (odd ? 1 : 0);
        uint32 word = odd ? ((pw[j] >> 16)     | (paw[j] & 0xFFFF0000u))
                          : ((paw[j] & 0xFFFFu) | (pw[j] << 16));
        *(uint32*)(ab + e*64 + ((np*4) ^ ((e & 3) << 4))) = word;
      }
    }
  };

  auto compute = [&](int buf){
    const char* ab = lds + buf*ASZ;
    const char* bb = lds + 2*ASZ + buf*BSZ;
    const int kswz = (((lane >> 4) ^ (lane & 3)) << 4);
    bf16x8 af[4], bfr[4];
    #pragma unroll
    for (int mi = 0; mi < 4; ++mi){
      int row = mi*16 + (lane & 15);
      af[mi] = *(const bf16x8*)(ab + row*64 + kswz);
    }
    #pragma unroll
    for (int fi = 0; fi < 4; ++fi){
      int row = w*64 + fi*16 + (lane & 15);
      bfr[fi] = *(const bf16x8*)(bb + row*64 + kswz);
    }
    #pragma unroll
    for (int mi = 0; mi < 4; ++mi){
      #pragma unroll
      for (int fi = 0; fi < 4; ++fi){
        acc[mi][fi] = __builtin_amdgcn_mfma_f32_16x16x32_bf16(af[mi], bfr[fi], acc[mi][fi], 0, 0, 0);
      }
    }
  };

  // prologue
  if (!GLA) loadA(0);
  gllB(0, 0);
  if (GLA) gllA(0, 0); else stageA(0);
  __syncthreads();

  int cur = 0;
  #pragma unroll 1
  for (int it = 0; it < NIT; ++it){
    if (it + 1 < NIT){
      if (!GLA) loadA(it + 1);
      gllB(it + 1, cur ^ 1);
      if (GLA) gllA(it + 1, cur ^ 1);
    }
    compute(cur);
    if (it + 1 < NIT && !GLA) stageA(cur ^ 1);
    __syncthreads();
    cur ^= 1;
  }

  // epilogue
  if (EPI == 0){
    float* C = Cpart + (size_t)s * (NMT*64) * 256;
    #pragma unroll
    for (int mi = 0; mi < 4; ++mi){
      int row0 = mt*64 + mi*16 + ((lane >> 4) * 4);
      #pragma unroll
      for (int fi = 0; fi < 4; ++fi){
        int f = w*64 + fi*16 + (lane & 15);
        #pragma unroll
        for (int r = 0; r < 4; ++r)
          C[(size_t)(row0 + r)*256 + f] = acc[mi][fi][r];
      }
    }
  } else {
    #pragma unroll
    for (int mi = 0; mi < 4; ++mi){
      int n0 = mt*64 + mi*16 + ((lane >> 4) * 4);
      float d0 = dvs[n0], d1 = dvs[n0+1], d2 = dvs[n0+2], d3 = dvs[n0+3];
      #pragma unroll
      for (int fi = 0; fi < 4; ++fi){
        int f = w*64 + fi*16 + (lane & 15);
        uint32 lo = pk2(acc[mi][fi][0]*d0, acc[mi][fi][1]*d1);
        uint32 hi = pk2(acc[mi][fi][2]*d2, acc[mi][fi][3]*d3);
        *(u32x2*)(XsT + (size_t)f*16384 + n0) = u32x2{lo, hi};
      }
    }
  }
}

// ---------------- mid: T1sT[f][e] = bf16( (sum_s T1part[s][e][f]) / (de[e]+eps) ) ----------------
// grid 1024, block 256 (f = tid, 4 e-rows per block)
__global__ void mid_kernel(const float* __restrict__ T1part, const float* __restrict__ de,
                           unsigned short* __restrict__ T1sT){
  int f = threadIdx.x;
  int e0 = blockIdx.x * 4;
  float v[4];
  #pragma unroll
  for (int r = 0; r < 4; ++r){
    float acc = 0.f;
    #pragma unroll
    for (int s = 0; s < 8; ++s)
      acc += T1part[(size_t)s*4096*256 + (size_t)(e0 + r)*256 + f];
    v[r] = acc / (de[e0 + r] + EPSC);
  }
  uint32 lo = pk2(v[0], v[1]);
  uint32 hi = pk2(v[2], v[3]);
  *(u32x2*)(T1sT + (size_t)f*4096 + e0) = u32x2{lo, hi};
}

// ---------------- fin: out[n][f] = relu(dvs[n] * (P0+P1)[n][f]), f32 ----------------
// grid 2048, block 256, 8 elems/thread
__global__ void fin_kernel(const float* __restrict__ P0, const float* __restrict__ P1,
                           const float* __restrict__ dvs, float* __restrict__ out){
  int gid = blockIdx.x*256 + threadIdx.x;
  int n = gid >> 5;
  int f0 = (gid & 31) * 8;
  size_t off = (size_t)n*256 + f0;
  f32x4_t a0 = *(const f32x4_t*)(P0 + off);
  f32x4_t a1 = *(const f32x4_t*)(P0 + off + 4);
  f32x4_t b0 = *(const f32x4_t*)(P1 + off);
  f32x4_t b1 = *(const f32x4_t*)(P1 + off + 4);
  float d = dvs[n];
  f32x4_t oa, ob;
  #pragma unroll
  for (int j = 0; j < 4; ++j){
    oa[j] = fmaxf((a0[j] + b0[j]) * d, 0.f);
    ob[j] = fmaxf((a1[j] + b1[j]) * d, 0.f);
  }
  *(f32x4_t*)(out + off) = oa;
  *(f32x4_t*)(out + off + 4) = ob;
}

extern "C" void kernel_launch(void* const* d_in, const int* in_sizes, int n_in,
                              void* d_out, int out_size, void* d_ws, size_t ws_size,
                              hipStream_t stream) {
  const float* emb = (const float*)d_in[0];   // [16384,256]
  const float* H   = (const float*)d_in[1];   // [16384,4096]
  const float* W   = (const float*)d_in[2];   // [256,256]
  float* out = (float*)d_out;                 // f32 [16384,256]

  char* ws = (char*)d_ws;
  float*          dvs    = (float*)(ws + 0);                  //   65536 B
  float*          de     = (float*)(ws + 65536);              //   16384 B
  unsigned short* WT     = (unsigned short*)(ws + 81920);     //  131072 B
  unsigned short* XsT    = (unsigned short*)(ws + 212992);    // 8388608 B  [256][16384] bf16
  unsigned short* T1sT   = (unsigned short*)(ws + 8601600);   // 2097152 B  [256][4096] bf16
  unsigned short* Hb     = (unsigned short*)(ws + 10698752);  // 134217728 B [16384][4096] bf16
  float*          T1part = (float*)(ws + 144916480);          // 33554432 B  [8][4096][256] f32
  float*          Opart  = (float*)(ws + 178470912);          // 33554432 B  [2][16384][256] f32
  // total ws usage: 212,025,344 B (< 1 GiB)

  zero_de<<<16, 256, 0, stream>>>(de);
  prep_wt<<<256, 256, 0, stream>>>(W, WT);

  // dv, de, Hb in one H pass
  deg_kernel<<<512, 256, 0, stream>>>(H, dvs, de, Hb);

  // X: XsT[f][n] = bf16(dvs[n] * (emb@W)[n][f]);  M=16384 (n), K=256 (c)
  gemm_k<0, 0, 1, 256, 256, 256, 256><<<256, 256, 0, stream>>>(emb, WT, nullptr, dvs, XsT);

  // GEMM1: T1part[s][e][f] = sum_{n in chunk s} Hb[n][e]*Xs[n][f];  M=4096 (e), K=16384 (n), split-K=8
  gemm_k<1, 1, 0, 4096, 16384, 64, 2048><<<512, 256, 0, stream>>>(Hb, XsT, T1part, nullptr, nullptr);

  // T1s = De^-1 * sum(T1part), bf16 transposed
  mid_kernel<<<1024, 256, 0, stream>>>(T1part, de, T1sT);

  // GEMM2: Opart[s][n][f] = sum_{e in chunk s} Hb[n][e]*T1s[e][f];  M=16384 (n), K=4096 (e), split-K=2
  gemm_k<0, 1, 0, 4096, 4096, 256, 2048><<<512, 256, 0, stream>>>(Hb, T1sT, Opart, nullptr, nullptr);

  // out = relu(dvs[n] * (Opart0 + Opart1))
  fin_kernel<<<2048, 256, 0, stream>>>(Opart, Opart + (size_t)16384*256, dvs, out);
}

// Round 4
// 247.108 us; speedup vs baseline: 1.2358x; 1.2358x over previous
//
#include <hip/hip_runtime.h>
#include <hip/hip_bf16.h>
#include <stdint.h>

typedef __attribute__((ext_vector_type(8))) __bf16 bf16x8;
typedef __attribute__((ext_vector_type(4))) float f32x4_t;
typedef __attribute__((ext_vector_type(2))) unsigned int u32x2;
typedef __attribute__((ext_vector_type(4))) unsigned int u32x4;
typedef unsigned int uint32;

#define EPSC 1e-6f

__device__ __forceinline__ unsigned short f2bf(float x){
  return __builtin_bit_cast(unsigned short, (__bf16)x);
}
__device__ __forceinline__ uint32 pk2(float a, float b){
  return (uint32)f2bf(a) | ((uint32)f2bf(b) << 16);
}

// ---------------- prep: WT[f][c] = bf16(W[c][f]) ----------------
__global__ void prep_wt(const float* __restrict__ W, unsigned short* __restrict__ WT){
  int c = blockIdx.x;   // 0..255
  int f = threadIdx.x;  // 0..255
  WT[(size_t)f*256 + c] = f2bf(W[(size_t)c*256 + f]);
}

// ---------------- hdeg: streaming H pass -> Hb bf16, row-sum partials, col-sum partials ----------------
// grid 1024 = (rb 0..255) x (cb 0..3); block 256 thr; block covers rows rb*64..+63, cols cb*1024..+1023
__global__ __launch_bounds__(256, 4)
void hdeg_kernel(const float* __restrict__ H, float* __restrict__ dvpart,
                 float* __restrict__ departial, unsigned short* __restrict__ Hb){
  __shared__ float wavepart[64][4];
  const int t = threadIdx.x;
  const int lane = t & 63;
  const int w = t >> 6;
  const int rb = blockIdx.x & 255;
  const int cb = blockIdx.x >> 8;
  const size_t colbase = (size_t)cb*1024 + t*4;
  f32x4_t dacc = {0.f, 0.f, 0.f, 0.f};
  #pragma unroll 4
  for (int r = 0; r < 64; ++r){
    const int n = rb*64 + r;
    f32x4_t v = *(const f32x4_t*)(H + (size_t)n*4096 + colbase);
    dacc[0] += v[0]; dacc[1] += v[1]; dacc[2] += v[2]; dacc[3] += v[3];
    *(u32x2*)(Hb + (size_t)n*4096 + colbase) = u32x2{pk2(v[0], v[1]), pk2(v[2], v[3])};
    float rs = (v[0] + v[1]) + (v[2] + v[3]);
    #pragma unroll
    for (int d = 1; d < 64; d <<= 1) rs += __shfl_xor(rs, d);
    if (lane == 0) wavepart[r][w] = rs;
  }
  // de partials: coalesced, no atomics
  *(f32x4_t*)(departial + (size_t)rb*4096 + cb*1024 + t*4) = dacc;
  __syncthreads();
  if (t < 64){
    float s = wavepart[t][0] + wavepart[t][1] + wavepart[t][2] + wavepart[t][3];
    dvpart[(size_t)cb*16384 + rb*64 + t] = s;
  }
}

// ---------------- fin_dvs: dvs[n] = rsqrt(sum_cb dvpart + eps); grid 64 ----------------
__global__ void fin_dvs(const float* __restrict__ dvpart, float* __restrict__ dvs){
  int n = blockIdx.x*256 + threadIdx.x;
  float s = dvpart[n] + dvpart[16384 + n] + dvpart[2*16384 + n] + dvpart[3*16384 + n];
  dvs[n] = rsqrtf(s + EPSC);
}

// ---------------- reduce_de: de[c] = sum_rb departial[rb][c]; grid 64 ----------------
__global__ void reduce_de(const float* __restrict__ departial, float* __restrict__ de){
  __shared__ float sm[4][64];
  int t = threadIdx.x;
  int c = blockIdx.x*64 + (t & 63);
  int part = t >> 6;
  float s = 0.f;
  #pragma unroll 4
  for (int rb = part*64; rb < part*64 + 64; ++rb)
    s += departial[(size_t)rb*4096 + c];
  sm[part][t & 63] = s;
  __syncthreads();
  if (t < 64) de[blockIdx.x*64 + t] = sm[0][t] + sm[1][t] + sm[2][t] + sm[3][t];
}

// ---------------- small MFMA GEMM (X = emb@W path only), verified round-2/3 code ----------------
// C[M,256] = A[M,K] @ BT[256,K]^T, A f32 reg-staged -> bf16. EPI=1: scale by dvs, store bf16 T to XsT.
template<int LDA, int KB, int NMT, int CHUNK>
__global__ __launch_bounds__(256, 2)
void gemm_x(const float* __restrict__ Af, const unsigned short* __restrict__ BT,
            const float* __restrict__ dvs, unsigned short* __restrict__ XsT)
{
  constexpr int NIT = CHUNK / 32;
  constexpr int ASZ = 64*32*2;
  constexpr int BSZ = 256*32*2;
  __shared__ __align__(16) char lds[2*ASZ + 2*BSZ];

  const int t = threadIdx.x;
  const int lane = t & 63;
  const int w = t >> 6;
  const int mt = blockIdx.x % NMT;
  const int s  = blockIdx.x / NMT;
  const int k0 = s * CHUNK;

  const int st_r  = t >> 2, st_cq = t & 3;

  f32x4_t acc[4][4] = {};
  f32x4_t pa[2];

  auto loadA = [&](int it){
    const float* p = Af + (size_t)(mt*64 + st_r)*LDA + k0 + it*32 + st_cq*4;
    pa[0] = *(const f32x4_t*)(p);
    pa[1] = *(const f32x4_t*)(p + 16);
  };

  auto gllB = [&](int it, int buf){
    char* bb = lds + 2*ASZ + buf*BSZ;
    const int kcur = k0 + it*32;
    const int swzh = ((lane & 3) ^ ((lane >> 2) & 3)) << 3;
    #pragma unroll
    for (int j = 0; j < 4; ++j){
      int chunk = w*4 + j;
      int frow = chunk*16 + (lane >> 2);
      const unsigned short* src = BT + (size_t)frow*KB + kcur + swzh;
      __builtin_amdgcn_global_load_lds((const __attribute__((address_space(1))) void*)src,
                                       (__attribute__((address_space(3))) void*)(bb + chunk*1024),
                                       16, 0, 0);
    }
  };

  auto stageA = [&](int buf){
    char* ab = lds + buf*ASZ;
    #pragma unroll
    for (int i = 0; i < 2; ++i){
      int f4 = st_cq + 4*i;
      uint32 lo = pk2(pa[i][0], pa[i][1]);
      uint32 hi = pk2(pa[i][2], pa[i][3]);
      *(u32x2*)(ab + st_r*64 + ((f4*8) ^ ((st_r & 3) << 4))) = u32x2{lo, hi};
    }
  };

  auto compute = [&](int buf){
    const char* ab = lds + buf*ASZ;
    const char* bb = lds + 2*ASZ + buf*BSZ;
    const int kswz = (((lane >> 4) ^ (lane & 3)) << 4);
    bf16x8 af[4], bfr[4];
    #pragma unroll
    for (int mi = 0; mi < 4; ++mi){
      int row = mi*16 + (lane & 15);
      af[mi] = *(const bf16x8*)(ab + row*64 + kswz);
    }
    #pragma unroll
    for (int fi = 0; fi < 4; ++fi){
      int row = w*64 + fi*16 + (lane & 15);
      bfr[fi] = *(const bf16x8*)(bb + row*64 + kswz);
    }
    #pragma unroll
    for (int mi = 0; mi < 4; ++mi){
      #pragma unroll
      for (int fi = 0; fi < 4; ++fi){
        acc[mi][fi] = __builtin_amdgcn_mfma_f32_16x16x32_bf16(af[mi], bfr[fi], acc[mi][fi], 0, 0, 0);
      }
    }
  };

  loadA(0);
  gllB(0, 0);
  stageA(0);
  __syncthreads();

  int cur = 0;
  #pragma unroll 1
  for (int it = 0; it < NIT; ++it){
    if (it + 1 < NIT){
      loadA(it + 1);
      gllB(it + 1, cur ^ 1);
    }
    compute(cur);
    if (it + 1 < NIT) stageA(cur ^ 1);
    __syncthreads();
    cur ^= 1;
  }

  #pragma unroll
  for (int mi = 0; mi < 4; ++mi){
    int n0 = mt*64 + mi*16 + ((lane >> 4) * 4);
    float d0 = dvs[n0], d1 = dvs[n0+1], d2 = dvs[n0+2], d3 = dvs[n0+3];
    #pragma unroll
    for (int fi = 0; fi < 4; ++fi){
      int f = w*64 + fi*16 + (lane & 15);
      uint32 lo = pk2(acc[mi][fi][0]*d0, acc[mi][fi][1]*d1);
      uint32 hi = pk2(acc[mi][fi][2]*d2, acc[mi][fi][3]*d3);
      *(u32x2*)(XsT + (size_t)f*16384 + n0) = u32x2{lo, hi};
    }
  }
}

// ---------------- big MFMA GEMM for the two H GEMMs: BM=128 x BN=256, BK=32, 512 thr ----------------
// C[M,256] = A[M,K] @ BT[256,K]^T, everything bf16 in, f32 split-K partials out.
// TRANS=0: A bf16 row-major [M][K] via global_load_lds (pre-swizzled source, B-convention).
// TRANS=1: A-logical = Asrc^T (Asrc bf16 [K][M]); shuffle-transpose staging, quarter-XOR pq = (np>>2)^((e>>3)&3).
template<int TRANS, int LDA, int KB, int NMT, int CHUNK>
__global__ __launch_bounds__(512, 1)
void gemm_h(const unsigned short* __restrict__ Ah, const unsigned short* __restrict__ BT,
            float* __restrict__ Cpart)
{
  constexpr int NIT = CHUNK / 32;
  constexpr int ASZ = 128*32*2;    // 8192 B
  constexpr int BSZ = 256*32*2;    // 16384 B
  __shared__ __align__(16) char lds[2*ASZ + 2*BSZ];  // 49152 B

  const int t = threadIdx.x;
  const int lane = t & 63;
  const int w = t >> 6;            // 0..7
  const int wm = w >> 2;           // 0..1  (m half)
  const int wf = w & 3;            // 0..3  (f quarter)
  const int mt = blockIdx.x % NMT;
  const int s  = blockIdx.x / NMT;
  const int k0 = s * CHUNK;

  f32x4_t acc[4][4] = {};
  u32x4 paw;                       // TRANS=1 staging regs

  auto gllB = [&](int it, int buf){
    char* bb = lds + 2*ASZ + buf*BSZ;
    const int kcur = k0 + it*32;
    const int swzh = ((lane & 3) ^ ((lane >> 2) & 3)) << 3;
    #pragma unroll
    for (int j = 0; j < 2; ++j){
      int chunk = w*2 + j;                       // 0..15
      int frow = chunk*16 + (lane >> 2);
      const unsigned short* src = BT + (size_t)frow*KB + kcur + swzh;
      __builtin_amdgcn_global_load_lds((const __attribute__((address_space(1))) void*)src,
                                       (__attribute__((address_space(3))) void*)(bb + chunk*1024),
                                       16, 0, 0);
    }
  };

  auto gllA = [&](int it, int buf){   // TRANS=0
    char* ab = lds + buf*ASZ;
    const int kcur = k0 + it*32;
    const int arow = lane >> 2;
    const int kqs  = (lane & 3) ^ (arow & 3);
    const unsigned short* src = Ah + (size_t)(mt*128 + w*16 + arow)*LDA + kcur + kqs*8;
    __builtin_amdgcn_global_load_lds((const __attribute__((address_space(1))) void*)src,
                                     (__attribute__((address_space(3))) void*)(ab + w*1024),
                                     16, 0, 0);
  };

  auto loadA_tr = [&](int it){        // TRANS=1: n = t>>4 (0..31), trq = t&15
    paw = *(const u32x4*)(Ah + (size_t)(k0 + it*32 + (t >> 4))*LDA + mt*128 + (t & 15)*8);
  };

  auto stageA_tr = [&](int buf){
    char* ab = lds + buf*ASZ;
    const int n = t >> 4;
    const int trq = t & 15;
    const bool odd = n & 1;
    const int np = n >> 1;           // 0..15
    uint32 pw[4];
    #pragma unroll
    for (int j = 0; j < 4; ++j) pw[j] = (uint32)__shfl_xor((int)paw[j], 16);
    #pragma unroll
    for (int j = 0; j < 4; ++j){
      int e = trq*8 + 2*j + (odd ? 1 : 0);
      uint32 word = odd ? ((pw[j] >> 16)      | (paw[j] & 0xFFFF0000u))
                        : ((paw[j] & 0xFFFFu) | (pw[j] << 16));
      int pq = (np >> 2) ^ (trq & 3);            // trq == e>>3
      *(uint32*)(ab + e*64 + pq*16 + (np & 3)*4) = word;
    }
  };

  auto compute = [&](int buf){
    const char* ab = lds + buf*ASZ;
    const char* bb = lds + 2*ASZ + buf*BSZ;
    const int l15 = lane & 15;
    const int kq = lane >> 4;
    bf16x8 af[4], bfr[4];
    #pragma unroll
    for (int mi = 0; mi < 4; ++mi){
      int row = wm*64 + mi*16 + l15;
      int q = TRANS ? (kq ^ ((row >> 3) & 3)) : (kq ^ (row & 3));
      af[mi] = *(const bf16x8*)(ab + row*64 + q*16);
    }
    #pragma unroll
    for (int fi = 0; fi < 4; ++fi){
      int row = wf*64 + fi*16 + l15;
      bfr[fi] = *(const bf16x8*)(bb + row*64 + ((kq ^ (l15 & 3)) << 4));
    }
    #pragma unroll
    for (int mi = 0; mi < 4; ++mi){
      #pragma unroll
      for (int fi = 0; fi < 4; ++fi){
        acc[mi][fi] = __builtin_amdgcn_mfma_f32_16x16x32_bf16(af[mi], bfr[fi], acc[mi][fi], 0, 0, 0);
      }
    }
  };

  // prologue
  if (TRANS) loadA_tr(0);
  gllB(0, 0);
  if (TRANS) stageA_tr(0); else gllA(0, 0);
  __syncthreads();

  int cur = 0;
  #pragma unroll 1
  for (int it = 0; it < NIT; ++it){
    if (it + 1 < NIT){
      if (TRANS) loadA_tr(it + 1);
      gllB(it + 1, cur ^ 1);
      if (!TRANS) gllA(it + 1, cur ^ 1);
    }
    compute(cur);
    if (TRANS && it + 1 < NIT) stageA_tr(cur ^ 1);
    __syncthreads();
    cur ^= 1;
  }

  // epilogue: f32 split-K partial, coalesced stores
  float* C = Cpart + (size_t)s * (NMT*128) * 256;
  #pragma unroll
  for (int mi = 0; mi < 4; ++mi){
    int row0 = mt*128 + wm*64 + mi*16 + ((lane >> 4) * 4);
    #pragma unroll
    for (int fi = 0; fi < 4; ++fi){
      int f = wf*64 + fi*16 + (lane & 15);
      #pragma unroll
      for (int r = 0; r < 4; ++r)
        C[(size_t)(row0 + r)*256 + f] = acc[mi][fi][r];
    }
  }
}

// ---------------- mid: T1sT[f][e] = bf16( (sum_s T1part[s][e][f]) / (de[e]+eps) ) ----------------
__global__ void mid_kernel(const float* __restrict__ T1part, const float* __restrict__ de,
                           unsigned short* __restrict__ T1sT){
  int f = threadIdx.x;
  int e0 = blockIdx.x * 4;
  float v[4];
  #pragma unroll
  for (int r = 0; r < 4; ++r){
    float acc = 0.f;
    #pragma unroll
    for (int s = 0; s < 8; ++s)
      acc += T1part[(size_t)s*4096*256 + (size_t)(e0 + r)*256 + f];
    v[r] = acc / (de[e0 + r] + EPSC);
  }
  uint32 lo = pk2(v[0], v[1]);
  uint32 hi = pk2(v[2], v[3]);
  *(u32x2*)(T1sT + (size_t)f*4096 + e0) = u32x2{lo, hi};
}

// ---------------- fin: out[n][f] = relu(dvs[n] * (P0+P1)[n][f]), f32 ----------------
__global__ void fin_kernel(const float* __restrict__ P0, const float* __restrict__ P1,
                           const float* __restrict__ dvs, float* __restrict__ out){
  int gid = blockIdx.x*256 + threadIdx.x;
  int n = gid >> 5;
  int f0 = (gid & 31) * 8;
  size_t off = (size_t)n*256 + f0;
  f32x4_t a0 = *(const f32x4_t*)(P0 + off);
  f32x4_t a1 = *(const f32x4_t*)(P0 + off + 4);
  f32x4_t b0 = *(const f32x4_t*)(P1 + off);
  f32x4_t b1 = *(const f32x4_t*)(P1 + off + 4);
  float d = dvs[n];
  f32x4_t oa, ob;
  #pragma unroll
  for (int j = 0; j < 4; ++j){
    oa[j] = fmaxf((a0[j] + b0[j]) * d, 0.f);
    ob[j] = fmaxf((a1[j] + b1[j]) * d, 0.f);
  }
  *(f32x4_t*)(out + off) = oa;
  *(f32x4_t*)(out + off + 4) = ob;
}

extern "C" void kernel_launch(void* const* d_in, const int* in_sizes, int n_in,
                              void* d_out, int out_size, void* d_ws, size_t ws_size,
                              hipStream_t stream) {
  const float* emb = (const float*)d_in[0];   // [16384,256]
  const float* H   = (const float*)d_in[1];   // [16384,4096]
  const float* W   = (const float*)d_in[2];   // [256,256]
  float* out = (float*)d_out;                 // f32 [16384,256]

  char* ws = (char*)d_ws;
  float*          dvs       = (float*)(ws + 0);                  //   65536 B
  float*          de        = (float*)(ws + 65536);              //   16384 B
  unsigned short* WT        = (unsigned short*)(ws + 81920);     //  131072 B
  unsigned short* XsT       = (unsigned short*)(ws + 212992);    // 8388608 B  [256][16384] bf16
  unsigned short* T1sT      = (unsigned short*)(ws + 8601600);   // 2097152 B  [256][4096] bf16
  unsigned short* Hb        = (unsigned short*)(ws + 10698752);  // 134217728 B [16384][4096] bf16
  float*          T1part    = (float*)(ws + 144916480);          // 33554432 B [8][4096][256]
  float*          Opart     = (float*)(ws + 178470912);          // 33554432 B [2][16384][256]
  float*          departial = (float*)(ws + 212025344);          // 4194304 B [256][4096]
  float*          dvpart    = (float*)(ws + 216219648);          // 262144 B [4][16384]
  // total ws usage: 216,481,792 B

  prep_wt<<<256, 256, 0, stream>>>(W, WT);

  // single streaming pass over H: Hb + degree partials
  hdeg_kernel<<<1024, 256, 0, stream>>>(H, dvpart, departial, Hb);
  fin_dvs<<<64, 256, 0, stream>>>(dvpart, dvs);
  reduce_de<<<64, 256, 0, stream>>>(departial, de);

  // X: XsT[f][n] = bf16(dvs[n] * (emb@W)[n][f]);  M=16384, K=256
  gemm_x<256, 256, 256, 256><<<256, 256, 0, stream>>>(emb, WT, dvs, XsT);

  // GEMM1: T1part[s][e][f] = sum_{n in chunk s} Hb[n][e]*Xs[n][f];  M=4096 (e), K=16384 (n), split-K=8
  gemm_h<1, 4096, 16384, 32, 2048><<<256, 512, 0, stream>>>(Hb, XsT, T1part);

  // T1s = De^-1 * sum(T1part), bf16 transposed
  mid_kernel<<<1024, 256, 0, stream>>>(T1part, de, T1sT);

  // GEMM2: Opart[s][n][f] = sum_{e in chunk s} Hb[n][e]*T1s[e][f];  M=16384 (n), K=4096 (e), split-K=2
  gemm_h<0, 4096, 4096, 128, 2048><<<256, 512, 0, stream>>>(Hb, T1sT, Opart);

  // out = relu(dvs[n] * (Opart0 + Opart1))
  fin_kernel<<<2048, 256, 0, stream>>>(Opart, Opart + (size_t)16384*256, dvs, out);
}